// Round 3
// baseline (332.130 us; speedup 1.0000x reference)
//
#include <hip/hip_runtime.h>

// ---------------------------------------------------------------------------
// CanonicalLinear: out[b,c] = sum_n factor[n] * (x @ W[n]^T + b[n])[b,c]
// Collapse heads: Weff = sum_n factor[n]*W[n] (C x D), beff = sum_n factor[n]*b[n]
// then out = x @ Weff^T + beff  -- single bf16 MFMA GEMM (m97 structure).
// Round 5 (this): prep = vmem-instruction-efficiency overhaul.
//   R2 evidence: prep ~84us but hbm_bytes/6.3TB/s = 23us, VALUBusy 3%,
//   deep-ILP gained only ~6% -> instruction-throughput bound, not latency.
//   Fix: every vmem instr is 16B (ushort8 stores; was 8B), in-flight regs
//   capped at 64 VGPR (old v[4][8] ~128+ VGPR risked scratch), nt hint
//   dropped (inputs are deliberately L3-resident). 17.8M -> 15.2M instrs,
//   all full-width. GEMM byte-identical (808 TF ~= m97 ceiling; 8-phase
//   port deferred until schedule can be race-screened).
// ---------------------------------------------------------------------------

#define MDIM 8192
#define KDIM 2048
#define NDIM 2048
#define NHEADS 8

#define BM 128
#define BN 128
#define BK 64

// prep geometry
#define WBLKS 1024   // W-reduce blocks
#define XBLKS 1024   // x-convert blocks
#define BBLKS 8      // bias blocks

using bf16x8 = __attribute__((ext_vector_type(8))) short;
using f32x4  = __attribute__((ext_vector_type(4))) float;
using f4v    = __attribute__((ext_vector_type(4))) float;
using u16x8  = __attribute__((ext_vector_type(8))) unsigned short;

__device__ __forceinline__ unsigned short f2bf(float x) {
    unsigned int u = __float_as_uint(x);
    u += 0x7FFFu + ((u >> 16) & 1u);
    return (unsigned short)(u >> 16);
}

__device__ __forceinline__ void async_load16(const void* g, void* l) {
    __builtin_amdgcn_global_load_lds(
        (const __attribute__((address_space(1))) unsigned int*)g,
        (__attribute__((address_space(3))) unsigned int*)l,
        16, 0, 0);
}

// --- fused prep: W-reduce -> bf16, x -> bf16, bias reduce -------------------
// Each thread owns groups of 8 CONSECUTIVE floats -> one 16 B bf16 store per
// group; loads are 2x float4 per group (lane-pair pattern, L1 merges lines).
// blocks [0, WBLKS):             Wbf[i..i+8) = bf16(sum_n f[n]*W[n][i..i+8))
//                                (2 groups/thread; 16 f4 loads in flight)
// blocks [WBLKS, WBLKS+XBLKS):   xbf = bf16(x)  (8 groups/thread)
// blocks [WBLKS+XBLKS, +BBLKS):  beff[c] = sum_n f[n]*b[n,c]
__global__ __launch_bounds__(256) void prep_kernel(
        const float* __restrict__ x,
        const float* __restrict__ W,
        const float* __restrict__ b,
        const float* __restrict__ factor,
        unsigned short* __restrict__ xbf,
        unsigned short* __restrict__ Wbf,
        float* __restrict__ beff) {
    const int blk = blockIdx.x;
    const int tid = threadIdx.x;
    if (blk < WBLKS) {
        const size_t CD      = (size_t)NDIM * KDIM;          // 4,194,304 floats/head
        const size_t tbase   = ((size_t)blk * 256 + tid) * 8;
        const size_t gstride = (size_t)WBLKS * 256 * 8;      // 2,097,152 floats
        float f[NHEADS];
#pragma unroll
        for (int n = 0; n < NHEADS; ++n) f[n] = factor[n];
#pragma unroll
        for (int g = 0; g < 2; ++g) {
            const size_t i = tbase + (size_t)g * gstride;
            f4v v0[NHEADS], v1[NHEADS];
#pragma unroll
            for (int n = 0; n < NHEADS; ++n) {
                const float* p = W + (size_t)n * CD + i;
                v0[n] = *reinterpret_cast<const f4v*>(p);
                v1[n] = *reinterpret_cast<const f4v*>(p + 4);
            }
            float a0 = 0.f, a1 = 0.f, a2 = 0.f, a3 = 0.f;
            float a4 = 0.f, a5 = 0.f, a6 = 0.f, a7 = 0.f;
#pragma unroll
            for (int n = 0; n < NHEADS; ++n) {
                a0 += f[n] * v0[n].x; a1 += f[n] * v0[n].y;
                a2 += f[n] * v0[n].z; a3 += f[n] * v0[n].w;
                a4 += f[n] * v1[n].x; a5 += f[n] * v1[n].y;
                a6 += f[n] * v1[n].z; a7 += f[n] * v1[n].w;
            }
            u16x8 o;
            o[0] = f2bf(a0); o[1] = f2bf(a1); o[2] = f2bf(a2); o[3] = f2bf(a3);
            o[4] = f2bf(a4); o[5] = f2bf(a5); o[6] = f2bf(a6); o[7] = f2bf(a7);
            *reinterpret_cast<u16x8*>(Wbf + i) = o;          // one 16 B store
        }
    } else if (blk < WBLKS + XBLKS) {
        const size_t tbase   = ((size_t)(blk - WBLKS) * 256 + tid) * 8;
        const size_t gstride = (size_t)XBLKS * 256 * 8;      // 2,097,152 floats
#pragma unroll
        for (int g = 0; g < 8; ++g) {
            const size_t i = tbase + (size_t)g * gstride;
            f4v v0 = *reinterpret_cast<const f4v*>(x + i);
            f4v v1 = *reinterpret_cast<const f4v*>(x + i + 4);
            u16x8 o;
            o[0] = f2bf(v0.x); o[1] = f2bf(v0.y); o[2] = f2bf(v0.z); o[3] = f2bf(v0.w);
            o[4] = f2bf(v1.x); o[5] = f2bf(v1.y); o[6] = f2bf(v1.z); o[7] = f2bf(v1.w);
            *reinterpret_cast<u16x8*>(xbf + i) = o;          // one 16 B store
        }
    } else {
        int c = (blk - WBLKS - XBLKS) * 256 + tid;
        float s = 0.f;
#pragma unroll
        for (int n = 0; n < NHEADS; ++n) s += factor[n] * b[(size_t)n * NDIM + c];
        beff[c] = s;
    }
}

// --- GEMM: out[m,c] = sum_k A[m,k]*B[c,k] + bias[c]  (B^T layout) -----------
// (byte-identical to R1/R2 baseline -- near m97-structure ceiling)
__global__ __launch_bounds__(256) void gemm_bt_kernel(
    const unsigned short* __restrict__ A,   // xbf  [MDIM][KDIM]
    const unsigned short* __restrict__ B,   // Wbf  [NDIM][KDIM]
    const float* __restrict__ bias,         // beff [NDIM]
    float* __restrict__ C)                  // out  [MDIM][NDIM] fp32
{
    __shared__ unsigned short As[BM * BK];  // 16 KB, unpadded (global_load_lds)
    __shared__ unsigned short Bs[BN * BK];  // 16 KB

    const int tid  = threadIdx.x;
    const int lane = tid & 63;
    const int w    = tid >> 6;      // wave 0..3
    const int m16  = lane & 15;
    const int quad = lane >> 4;     // 0..3

    // XCD-aware swizzle: xcd = bid&7 owns N-tiles {2*xcd, 2*xcd+1} (1 MB of B
    // -> L2-resident per XCD); A streams through once per XCD.
    const int bid = blockIdx.x;
    const int g   = bid >> 3;
    const int nt  = (bid & 7) * 2 + (g & 1);
    const int mt  = g >> 1;
    const int blockN0 = nt * BN;
    const int blockM0 = mt * BM;

    const int wr = (w >> 1) * 64;   // wave's row quadrant in tile
    const int wc = (w & 1) * 64;    // wave's col quadrant

    // staging: lane deposits 16 B at LDS slot (srow, lane&7)  [HW-fixed order];
    // we XOR-swizzle the GLOBAL column group so LDS group gl holds global
    // group gl ^ (row&7) -> fragment reads spread across all 8 bank-groups.
    const int srow = lane >> 3;                    // 0..7 (row&7 of this lane's row)
    const int scol = ((lane & 7) ^ srow) * 8;      // swizzled global bf16 col
    const unsigned short* aP[4];
    const unsigned short* bP[4];
    unsigned short* aL[4];
    unsigned short* bL[4];
#pragma unroll
    for (int i = 0; i < 4; ++i) {
        int r = i * 32 + w * 8;
        aP[i] = A + (size_t)(blockM0 + r + srow) * KDIM + scol;
        bP[i] = B + (size_t)(blockN0 + r + srow) * KDIM + scol;
        aL[i] = As + (size_t)r * BK;               // wave-uniform LDS base
        bL[i] = Bs + (size_t)r * BK;
    }

    f32x4 acc[4][4] = {};

    for (int k0 = 0; k0 < KDIM; k0 += BK) {
#pragma unroll
        for (int i = 0; i < 4; ++i) {
            async_load16(aP[i], aL[i]);
            async_load16(bP[i], bL[i]);
            aP[i] += BK; bP[i] += BK;
        }
        __syncthreads();

#pragma unroll
        for (int kk = 0; kk < BK; kk += 32) {
            bf16x8 af[4], bfr[4];
#pragma unroll
            for (int rt = 0; rt < 4; ++rt) {
                int row = wr + rt * 16 + m16;
                int gA = ((kk >> 3) + quad) ^ (row & 7);   // un-swizzle
                af[rt] = *reinterpret_cast<const bf16x8*>(&As[(size_t)row * BK + gA * 8]);
            }
#pragma unroll
            for (int ct = 0; ct < 4; ++ct) {
                int row = wc + ct * 16 + m16;
                int gB = ((kk >> 3) + quad) ^ (row & 7);
                bfr[ct] = *reinterpret_cast<const bf16x8*>(&Bs[(size_t)row * BK + gB * 8]);
            }
#pragma unroll
            for (int rt = 0; rt < 4; ++rt)
#pragma unroll
                for (int ct = 0; ct < 4; ++ct)
                    acc[rt][ct] = __builtin_amdgcn_mfma_f32_16x16x32_bf16(
                        af[rt], bfr[ct], acc[rt][ct], 0, 0, 0);
        }
        __syncthreads();
    }

    // epilogue: C/D layout col=lane&15, row=quad*4+reg (verified m89/m91)
    float bv[4];
#pragma unroll
    for (int ct = 0; ct < 4; ++ct) bv[ct] = bias[blockN0 + wc + ct * 16 + m16];
#pragma unroll
    for (int rt = 0; rt < 4; ++rt) {
        int row0 = blockM0 + wr + rt * 16 + quad * 4;
#pragma unroll
        for (int ct = 0; ct < 4; ++ct) {
            int col = blockN0 + wc + ct * 16 + m16;
#pragma unroll
            for (int r = 0; r < 4; ++r)
                C[(size_t)(row0 + r) * NDIM + col] = acc[rt][ct][r] + bv[ct];
        }
    }
}

extern "C" void kernel_launch(void* const* d_in, const int* in_sizes, int n_in,
                              void* d_out, int out_size, void* d_ws, size_t ws_size,
                              hipStream_t stream) {
    const float* x      = (const float*)d_in[0];   // [8192][2048]
    const float* W      = (const float*)d_in[1];   // [8][2048][2048]
    const float* b      = (const float*)d_in[2];   // [8][2048]
    const float* factor = (const float*)d_in[3];   // [8]
    float* out = (float*)d_out;                    // [8192][2048]

    unsigned short* xbf  = (unsigned short*)d_ws;                         // 33,554,432 B
    unsigned short* Wbf  = (unsigned short*)((char*)d_ws + 33554432);     //  8,388,608 B
    float*          beff = (float*)((char*)d_ws + 33554432 + 8388608);    //      8,192 B

    prep_kernel<<<dim3(WBLKS + XBLKS + BBLKS), dim3(256), 0, stream>>>(
        x, W, b, factor, xbf, Wbf, beff);
    gemm_bt_kernel<<<dim3(1024), dim3(256), 0, stream>>>(xbf, Wbf, beff, out);
}